// Round 1
// baseline (883.272 us; speedup 1.0000x reference)
//
#include <hip/hip_runtime.h>

#define NTOK 8192
#define DDIM 1024
#define HDIM 2048
#define NEXP 8

typedef unsigned short u16;
typedef short bf16x8 __attribute__((ext_vector_type(8)));
typedef float f32x4 __attribute__((ext_vector_type(4)));
typedef float float4_t __attribute__((ext_vector_type(4)));

__device__ __forceinline__ u16 f2bf(float f) {
  unsigned u = __float_as_uint(f);
  u += 0x7FFFu + ((u >> 16) & 1u);   // round-to-nearest-even
  return (u16)(u >> 16);
}

#define GLOAD_LDS16(gp, lp)                                                     \
  __builtin_amdgcn_global_load_lds(                                             \
      (const __attribute__((address_space(1))) unsigned int*)(gp),              \
      (__attribute__((address_space(3))) unsigned int*)(lp), 16, 0, 0)

// ---------------------------------------------------------------- convert x
__global__ void k_cvt(const float* __restrict__ in, u16* __restrict__ out, int n8) {
  int i = blockIdx.x * 256 + threadIdx.x;
  if (i >= n8) return;
  const float4_t* p = (const float4_t*)in + (size_t)i * 2;
  float4_t a = p[0], b = p[1];
  union { bf16x8 v; u16 s[8]; } u;
  u.s[0] = f2bf(a.x); u.s[1] = f2bf(a.y); u.s[2] = f2bf(a.z); u.s[3] = f2bf(a.w);
  u.s[4] = f2bf(b.x); u.s[5] = f2bf(b.y); u.s[6] = f2bf(b.z); u.s[7] = f2bf(b.w);
  ((bf16x8*)out)[i] = u.v;
}

// ------------------------------------------- transpose+convert: out[c][r]=in[r][c]
__global__ void k_transpose(const float* __restrict__ in, u16* __restrict__ out,
                            int R, int C) {
  __shared__ float t[64][65];
  int rb = blockIdx.x * 64, cb = blockIdx.y * 64;
  size_t eo = (size_t)blockIdx.z * R * C;
  const float* pin = in + eo;
  u16* pout = out + eo;
  int tr = threadIdx.x >> 6;   // 0..3
  int tc = threadIdx.x & 63;
#pragma unroll
  for (int i = 0; i < 64; i += 4)
    t[tr + i][tc] = pin[(size_t)(rb + tr + i) * C + cb + tc];
  __syncthreads();
#pragma unroll
  for (int i = 0; i < 64; i += 4)
    pout[(size_t)(cb + tr + i) * R + rb + tc] = f2bf(t[tc][tr + i]);
}

// ---------------------------------------------------------------- gate (fp32)
__global__ void k_gate(const float* __restrict__ x, const float* __restrict__ Wg,
                       const float* __restrict__ bg, float* __restrict__ gate) {
  int tok = (blockIdx.x * 256 + threadIdx.x) >> 6;
  int lane = threadIdx.x & 63;
  const float* xr = x + (size_t)tok * DDIM;
  float s[NEXP];
#pragma unroll
  for (int e = 0; e < NEXP; ++e) s[e] = 0.f;
  for (int k = lane; k < DDIM; k += 64) {
    float xv = xr[k];
    const float* wr = Wg + (size_t)k * NEXP;
#pragma unroll
    for (int e = 0; e < NEXP; ++e) s[e] += xv * wr[e];
  }
#pragma unroll
  for (int off = 32; off; off >>= 1)
#pragma unroll
    for (int e = 0; e < NEXP; ++e) s[e] += __shfl_down(s[e], off);
  if (lane == 0) {
#pragma unroll
    for (int e = 0; e < NEXP; ++e) gate[(size_t)tok * NEXP + e] = s[e] + bg[e];
  }
}

// ---------------------------------------------------------------- GEMM (m97-style)
// C[M][N] = A[M][K] * Bt[N][K]^T ; MODE 1: h' = bf16(gate*relu(acc+bias))
//                                  MODE 2: out fp32 (+)= acc + gate*bias
template <int MODE>
__global__ __launch_bounds__(256) void k_gemm(
    const u16* __restrict__ A, int lda,
    const u16* __restrict__ Bt, int ldb,
    const float* __restrict__ bias,
    const float* __restrict__ gate, int e,
    void* __restrict__ Cout, int ldc,
    int tilesN, int K, int accum) {
  __shared__ __align__(16) u16 ldsA[128 * 64];
  __shared__ __align__(16) u16 ldsB[128 * 64];
  const int tid = threadIdx.x;
  const int lane = tid & 63;
  const int wid = tid >> 6;

  // bijective XCD swizzle (m204)
  int nwg = gridDim.x;
  int wg = blockIdx.x;
  int q = nwg >> 3, r8 = nwg & 7;
  int xcd = wg & 7, lo = wg >> 3;
  int swz = (xcd < r8 ? xcd * (q + 1) : r8 * (q + 1) + (xcd - r8) * q) + lo;
  int tm = swz / tilesN, tn = swz % tilesN;
  int bm = tm * 128, bn = tn * 128;

  // staging: chunk c = is*4+wid covers LDS bytes [c*1024, c*1024+1024)
  // linear LDS dest + inverse-XOR-swizzled global source (rule 21)
  const int lr = lane >> 3;                 // row within 8-row chunk
  const int lc = ((lane & 7) ^ lr) << 3;    // swizzled col offset (elements)
  const u16* pA = A + (size_t)(bm + wid * 8 + lr) * lda + lc;
  const u16* pB = Bt + (size_t)(bn + wid * 8 + lr) * ldb + lc;
  u16* sA = ldsA + wid * 512;
  u16* sB = ldsB + wid * 512;

  const int fr = lane & 15;
  const int fq = lane >> 4;
  const int wr = wid >> 1, wc = wid & 1;

  f32x4 acc[4][4] = {};

  const int nkt = K >> 6;
#pragma unroll 1
  for (int kt = 0; kt < nkt; ++kt) {
#pragma unroll
    for (int is = 0; is < 4; ++is) {
      GLOAD_LDS16(pA + (size_t)is * 32 * lda, sA + is * 2048);
      GLOAD_LDS16(pB + (size_t)is * 32 * ldb, sB + is * 2048);
    }
    pA += 64; pB += 64;
    __syncthreads();
#pragma unroll
    for (int kk = 0; kk < 2; ++kk) {
      bf16x8 af[4], bfr[4];
#pragma unroll
      for (int m = 0; m < 4; ++m) {
        int row = wr * 64 + m * 16 + fr;
        int eoff = (row << 6) + ((((kk << 2) + fq) ^ (row & 7)) << 3);
        af[m] = *(const bf16x8*)(ldsA + eoff);
      }
#pragma unroll
      for (int n = 0; n < 4; ++n) {
        int row = wc * 64 + n * 16 + fr;
        int eoff = (row << 6) + ((((kk << 2) + fq) ^ (row & 7)) << 3);
        bfr[n] = *(const bf16x8*)(ldsB + eoff);
      }
#pragma unroll
      for (int m = 0; m < 4; ++m)
#pragma unroll
        for (int n = 0; n < 4; ++n)
          acc[m][n] = __builtin_amdgcn_mfma_f32_16x16x32_bf16(af[m], bfr[n],
                                                              acc[m][n], 0, 0, 0);
    }
    __syncthreads();
  }

  // epilogue: C/D layout col=lane&15, row=(lane>>4)*4+j  [m89/m91 verified]
  const int colbase = bn + wc * 64 + fr;
  float bcol[4];
#pragma unroll
  for (int n = 0; n < 4; ++n) bcol[n] = bias[colbase + n * 16];
#pragma unroll
  for (int m = 0; m < 4; ++m) {
#pragma unroll
    for (int j = 0; j < 4; ++j) {
      int r = bm + wr * 64 + m * 16 + fq * 4 + j;
      float g = gate[(size_t)r * NEXP + e];
      if (MODE == 1) {
        u16* O = (u16*)Cout;
#pragma unroll
        for (int n = 0; n < 4; ++n) {
          float v = acc[m][n][j] + bcol[n];
          v = fmaxf(v, 0.f) * g;
          O[(size_t)r * ldc + colbase + n * 16] = f2bf(v);
        }
      } else {
        float* O = (float*)Cout;
#pragma unroll
        for (int n = 0; n < 4; ++n) {
          float v = acc[m][n][j] + g * bcol[n];
          size_t idx = (size_t)r * ldc + colbase + n * 16;
          if (accum) v += O[idx];
          O[idx] = v;
        }
      }
    }
  }
}

extern "C" void kernel_launch(void* const* d_in, const int* in_sizes, int n_in,
                              void* d_out, int out_size, void* d_ws, size_t ws_size,
                              hipStream_t stream) {
  (void)in_sizes; (void)n_in; (void)out_size;
  const float* x  = (const float*)d_in[0];   // [N, D]
  const float* W1 = (const float*)d_in[1];   // [E, D, H]
  const float* b1 = (const float*)d_in[2];   // [E, H]
  const float* W2 = (const float*)d_in[3];   // [E, H, D]
  const float* b2 = (const float*)d_in[4];   // [E, D]
  const float* Wg = (const float*)d_in[5];   // [D, E]
  const float* bg = (const float*)d_in[6];   // [E]
  float* out = (float*)d_out;                // [N, D]

  // workspace layout
  size_t o_xb   = 0;
  size_t o_w1t  = o_xb  + (size_t)NTOK * DDIM * 2;          // xb  bf16 [N,D]
  size_t o_w2t  = o_w1t + (size_t)NEXP * HDIM * DDIM * 2;   // W1t bf16 [E,H,D]
  size_t o_gate = o_w2t + (size_t)NEXP * DDIM * HDIM * 2;   // W2t bf16 [E,D,H]
  size_t o_h    = o_gate + (size_t)NTOK * NEXP * 4;         // gate f32 [N,E]
  size_t need   = o_h   + (size_t)NTOK * HDIM * 2;          // h'  bf16 [N,H]
  if (ws_size < need) return;  // insufficient workspace — adapt next round
  u16*   xb   = (u16*)((char*)d_ws + o_xb);
  u16*   W1t  = (u16*)((char*)d_ws + o_w1t);
  u16*   W2t  = (u16*)((char*)d_ws + o_w2t);
  float* gate = (float*)((char*)d_ws + o_gate);
  u16*   hbuf = (u16*)((char*)d_ws + o_h);

  k_cvt<<<(NTOK * DDIM / 8 + 255) / 256, 256, 0, stream>>>(x, xb, NTOK * DDIM / 8);
  dim3 g1(DDIM / 64, HDIM / 64, NEXP);
  k_transpose<<<g1, 256, 0, stream>>>(W1, W1t, DDIM, HDIM);
  dim3 g2(HDIM / 64, DDIM / 64, NEXP);
  k_transpose<<<g2, 256, 0, stream>>>(W2, W2t, HDIM, DDIM);
  k_gate<<<NTOK / 4, 256, 0, stream>>>(x, Wg, bg, gate);

  for (int e = 0; e < NEXP; ++e) {
    const u16* w1e = W1t + (size_t)e * HDIM * DDIM;
    const u16* w2e = W2t + (size_t)e * DDIM * HDIM;
    k_gemm<1><<<(NTOK / 128) * (HDIM / 128), 256, 0, stream>>>(
        xb, DDIM, w1e, DDIM, b1 + (size_t)e * HDIM, gate, e,
        hbuf, HDIM, HDIM / 128, DDIM, 0);
    k_gemm<2><<<(NTOK / 128) * (DDIM / 128), 256, 0, stream>>>(
        hbuf, HDIM, w2e, HDIM, b2 + (size_t)e * DDIM, gate, e,
        out, DDIM, DDIM / 128, HDIM, e > 0);
  }
}

// Round 2
// 683.457 us; speedup vs baseline: 1.2924x; 1.2924x over previous
//
#include <hip/hip_runtime.h>

#define NTOK 8192
#define DDIM 1024
#define HDIM 2048
#define NEXP 8

#define BM 256
#define BN 128
#define BK 64

typedef unsigned short u16;
typedef short bf16x8 __attribute__((ext_vector_type(8)));
typedef float f32x4 __attribute__((ext_vector_type(4)));
typedef float float4_t __attribute__((ext_vector_type(4)));

__device__ __forceinline__ u16 f2bf(float f) {
  unsigned u = __float_as_uint(f);
  u += 0x7FFFu + ((u >> 16) & 1u);   // round-to-nearest-even
  return (u16)(u >> 16);
}

#define GLOAD_LDS16(gp, lp)                                                     \
  __builtin_amdgcn_global_load_lds(                                             \
      (const __attribute__((address_space(1))) unsigned int*)(gp),              \
      (__attribute__((address_space(3))) unsigned int*)(lp), 16, 0, 0)

// ---------------------------------------------------------------- convert x
__global__ void k_cvt(const float* __restrict__ in, u16* __restrict__ out, int n8) {
  int i = blockIdx.x * 256 + threadIdx.x;
  if (i >= n8) return;
  const float4_t* p = (const float4_t*)in + (size_t)i * 2;
  float4_t a = p[0], b = p[1];
  union { bf16x8 v; u16 s[8]; } u;
  u.s[0] = f2bf(a.x); u.s[1] = f2bf(a.y); u.s[2] = f2bf(a.z); u.s[3] = f2bf(a.w);
  u.s[4] = f2bf(b.x); u.s[5] = f2bf(b.y); u.s[6] = f2bf(b.z); u.s[7] = f2bf(b.w);
  ((bf16x8*)out)[i] = u.v;
}

// ------------------- transpose+convert: out[obase + c*orstride + r] = in[r][c]
// per-expert input at in + z*R*C; obase = z*oexp
__global__ void k_transpose(const float* __restrict__ in, u16* __restrict__ out,
                            int R, int C, size_t oexp, int orstride) {
  __shared__ float t[64][65];
  int rb = blockIdx.x * 64, cb = blockIdx.y * 64;
  const float* pin = in + (size_t)blockIdx.z * R * C;
  u16* pout = out + (size_t)blockIdx.z * oexp;
  int tr = threadIdx.x >> 6;   // 0..3
  int tc = threadIdx.x & 63;
#pragma unroll
  for (int i = 0; i < 64; i += 4)
    t[tr + i][tc] = pin[(size_t)(rb + tr + i) * C + cb + tc];
  __syncthreads();
#pragma unroll
  for (int i = 0; i < 64; i += 4)
    pout[(size_t)(cb + tr + i) * orstride + rb + tc] = f2bf(t[tc][tr + i]);
}

// ---------------------------------------------------------------- gate (fp32)
__global__ void k_gate(const float* __restrict__ x, const float* __restrict__ Wg,
                       const float* __restrict__ bg, float* __restrict__ gate) {
  int tok = (blockIdx.x * 256 + threadIdx.x) >> 6;
  int lane = threadIdx.x & 63;
  const float* xr = x + (size_t)tok * DDIM;
  float s[NEXP];
#pragma unroll
  for (int e = 0; e < NEXP; ++e) s[e] = 0.f;
  for (int k = lane; k < DDIM; k += 64) {
    float xv = xr[k];
    const float* wr = Wg + (size_t)k * NEXP;
#pragma unroll
    for (int e = 0; e < NEXP; ++e) s[e] += xv * wr[e];
  }
#pragma unroll
  for (int off = 32; off; off >>= 1)
#pragma unroll
    for (int e = 0; e < NEXP; ++e) s[e] += __shfl_down(s[e], off);
  if (lane == 0) {
#pragma unroll
    for (int e = 0; e < NEXP; ++e) gate[(size_t)tok * NEXP + e] = s[e] + bg[e];
  }
}

// --------------------------------------------- pipelined GEMM (3-buf, counted vmcnt)
// C[M][N] = A[M][K] * Bt[N][K]^T
// MODE 1: h' = bf16(gate * relu(acc + bias))     (bias = b1 slice, ldc = group N)
// MODE 2: out f32 (+)= acc (+ sum_e gate*b2 when !accum)
template <int MODE>
__global__ __launch_bounds__(512, 2) void k_gemm(
    const u16* __restrict__ A, int lda,
    const u16* __restrict__ Bt, int ldb,
    const float* __restrict__ bias,
    const float* __restrict__ gate, int ebase,
    void* __restrict__ Cout, int ldc,
    int tilesN, int K, int accum) {
  __shared__ __align__(16) u16 lds[3 * (BM + BN) * BK];  // 144 KiB
  const int tid = threadIdx.x;
  const int lane = tid & 63;
  const int wid = tid >> 6;      // 0..7
  const int wm = wid >> 1;       // 0..3 (M)
  const int wn = wid & 1;        // 0..1 (N)

  // bijective XCD swizzle (m204)
  int nwg = gridDim.x, wg = blockIdx.x;
  int q = nwg >> 3, r8 = nwg & 7;
  int xcd = wg & 7, lo = wg >> 3;
  int swz = (xcd < r8 ? xcd * (q + 1) : r8 * (q + 1) + (xcd - r8) * q) + lo;
  int tm = swz / tilesN, tn = swz % tilesN;
  int bm = tm * BM, bn = tn * BN;

  // --- staging addresses: linear LDS dest + inverse-swizzled global source
  const int srow = tid >> 3;                        // 0..63
  const int scol = ((tid & 7) ^ (srow & 7)) << 3;   // swizzled col (elems)
  const u16* gA = A + (size_t)(bm + srow) * lda + scol;
  const u16* gB = Bt + (size_t)(bn + srow) * ldb + scol;
  const int dofs = wid * 512;                       // per-wave LDS chunk (elems)

  u16* a0 = lds;            u16* b0 = lds + BM * BK;
  u16* a1 = b0 + BN * BK;   u16* b1p = a1 + BM * BK;
  u16* a2 = b1p + BN * BK;  u16* b2p = a2 + BM * BK;

#define STAGE(aD, bD, kt)                                                       \
  {                                                                             \
    const u16* sa_ = gA + (size_t)(kt) * BK;                                    \
    const u16* sb_ = gB + (size_t)(kt) * BK;                                    \
    GLOAD_LDS16(sa_,                       (aD) + dofs);                        \
    GLOAD_LDS16(sa_ + (size_t)64 * lda,    (aD) + 4096 + dofs);                 \
    GLOAD_LDS16(sa_ + (size_t)128 * lda,   (aD) + 8192 + dofs);                 \
    GLOAD_LDS16(sa_ + (size_t)192 * lda,   (aD) + 12288 + dofs);                \
    GLOAD_LDS16(sb_,                       (bD) + dofs);                        \
    GLOAD_LDS16(sb_ + (size_t)64 * ldb,    (bD) + 4096 + dofs);                 \
  }

  // --- fragment read offsets (swizzled)
  const int fr = lane & 15;
  const int fq = lane >> 4;
  const int xr = fr & 7;
  const int so0 = ((0 + fq) ^ xr) << 3;   // kk=0 slot (elems)
  const int so1 = ((4 + fq) ^ xr) << 3;   // kk=1 slot
  int aro[4], bro[4];
#pragma unroll
  for (int m = 0; m < 4; ++m) aro[m] = (wm * 64 + m * 16 + fr) << 6;
#pragma unroll
  for (int n = 0; n < 4; ++n) bro[n] = (wn * 64 + n * 16 + fr) << 6;

  f32x4 acc[4][4] = {};
  const int nkt = K >> 6;

  // prologue: stage tiles 0,1; guarantee tile 0 resident, keep tile 1 in flight
  STAGE(a0, b0, 0);
  STAGE(a1, b1p, 1);
  asm volatile("s_waitcnt vmcnt(6)" ::: "memory");
  __builtin_amdgcn_s_barrier();
  __builtin_amdgcn_sched_barrier(0);

  u16 *aC = a0, *bC = b0, *aN = a1, *bN = b1p, *aF = a2, *bF = b2p;

#pragma unroll 1
  for (int t = 0; t < nkt; ++t) {
    if (t + 2 < nkt) STAGE(aF, bF, t + 2);   // safe: buf last read at t-1, barrier passed
#pragma unroll
    for (int kk = 0; kk < 2; ++kk) {
      const int so = kk ? so1 : so0;
      bf16x8 af[4], bfv[4];
#pragma unroll
      for (int m = 0; m < 4; ++m) af[m] = *(const bf16x8*)(aC + aro[m] + so);
#pragma unroll
      for (int n = 0; n < 4; ++n) bfv[n] = *(const bf16x8*)(bC + bro[n] + so);
      __builtin_amdgcn_s_setprio(1);
#pragma unroll
      for (int m = 0; m < 4; ++m)
#pragma unroll
        for (int n = 0; n < 4; ++n)
          acc[m][n] = __builtin_amdgcn_mfma_f32_16x16x32_bf16(af[m], bfv[n],
                                                              acc[m][n], 0, 0, 0);
      __builtin_amdgcn_s_setprio(0);
    }
    if (t != nkt - 1) {
      if (t + 2 < nkt) {
        asm volatile("s_waitcnt vmcnt(6)" ::: "memory");  // t+1 landed, t+2 in flight
      } else {
        asm volatile("s_waitcnt vmcnt(0)" ::: "memory");
      }
      __builtin_amdgcn_s_barrier();
      __builtin_amdgcn_sched_barrier(0);
      u16* tp;
      tp = aC; aC = aN; aN = aF; aF = tp;
      tp = bC; bC = bN; bN = bF; bF = tp;
    }
  }

  // ---------------- epilogue; C/D layout: col=lane&15, row=(lane>>4)*4+j
  const int colbase = bn + wn * 64 + fr;
  if (MODE == 1) {
    const int e = ebase + ((bn + wn * 64) >> 11);   // 64-col wave tile never crosses expert
    float bcol[4];
#pragma unroll
    for (int n = 0; n < 4; ++n) bcol[n] = bias[colbase + n * 16];
    u16* O = (u16*)Cout;
#pragma unroll
    for (int m = 0; m < 4; ++m) {
#pragma unroll
      for (int j = 0; j < 4; ++j) {
        int r = bm + wm * 64 + m * 16 + fq * 4 + j;
        float g = gate[(size_t)r * NEXP + e];
#pragma unroll
        for (int n = 0; n < 4; ++n) {
          float v = fmaxf(acc[m][n][j] + bcol[n], 0.f) * g;
          O[(size_t)r * ldc + colbase + n * 16] = f2bf(v);
        }
      }
    }
  } else {
    float* O = (float*)Cout;
    float b2c[4][NEXP];
    if (!accum) {
#pragma unroll
      for (int n = 0; n < 4; ++n)
#pragma unroll
        for (int e = 0; e < NEXP; ++e)
          b2c[n][e] = bias[(size_t)e * DDIM + colbase + n * 16];
    }
#pragma unroll
    for (int m = 0; m < 4; ++m) {
#pragma unroll
      for (int j = 0; j < 4; ++j) {
        int r = bm + wm * 64 + m * 16 + fq * 4 + j;
        if (!accum) {
          float g8[NEXP];
#pragma unroll
          for (int e = 0; e < NEXP; ++e) g8[e] = gate[(size_t)r * NEXP + e];
#pragma unroll
          for (int n = 0; n < 4; ++n) {
            float v = acc[m][n][j];
#pragma unroll
            for (int e = 0; e < NEXP; ++e) v += g8[e] * b2c[n][e];
            O[(size_t)r * DDIM + colbase + n * 16] = v;
          }
        } else {
#pragma unroll
          for (int n = 0; n < 4; ++n) {
            size_t idx = (size_t)r * DDIM + colbase + n * 16;
            O[idx] += acc[m][n][j];
          }
        }
      }
    }
  }
#undef STAGE
}

extern "C" void kernel_launch(void* const* d_in, const int* in_sizes, int n_in,
                              void* d_out, int out_size, void* d_ws, size_t ws_size,
                              hipStream_t stream) {
  (void)in_sizes; (void)n_in; (void)out_size;
  const float* x  = (const float*)d_in[0];   // [N, D]
  const float* W1 = (const float*)d_in[1];   // [E, D, H]
  const float* b1 = (const float*)d_in[2];   // [E, H]
  const float* W2 = (const float*)d_in[3];   // [E, H, D]
  const float* b2 = (const float*)d_in[4];   // [E, D]
  const float* Wg = (const float*)d_in[5];   // [D, E]
  const float* bg = (const float*)d_in[6];   // [E]
  float* out = (float*)d_out;                // [N, D]

  // workspace layout
  size_t o_xb   = 0;
  size_t o_w1t  = o_xb  + (size_t)NTOK * DDIM * 2;          // xb   bf16 [N,D]
  size_t o_w2t  = o_w1t + (size_t)NEXP * HDIM * DDIM * 2;   // W1t  bf16 [E*H, D]
  size_t o_gate = o_w2t + (size_t)NEXP * DDIM * HDIM * 2;   // W2t  bf16 [D, E*H]
  size_t o_h    = o_gate + (size_t)NTOK * NEXP * 4;         // gate f32  [N, E]
  size_t base   = o_h;

  int G = 8;                                                 // experts per group
  while (G > 1 && base + (size_t)NTOK * G * HDIM * 2 > ws_size) G >>= 1;
  if (base + (size_t)NTOK * G * HDIM * 2 > ws_size) return;

  u16*   xb   = (u16*)((char*)d_ws + o_xb);
  u16*   W1t  = (u16*)((char*)d_ws + o_w1t);
  u16*   W2t  = (u16*)((char*)d_ws + o_w2t);
  float* gate = (float*)((char*)d_ws + o_gate);
  u16*   hbuf = (u16*)((char*)d_ws + o_h);

  k_cvt<<<(NTOK * DDIM / 8 + 255) / 256, 256, 0, stream>>>(x, xb, NTOK * DDIM / 8);
  // W1[e][d][h] -> W1t[e*H + h][d]   (oexp = H*D rows block, row stride D)
  dim3 g1(DDIM / 64, HDIM / 64, NEXP);
  k_transpose<<<g1, 256, 0, stream>>>(W1, W1t, DDIM, HDIM, (size_t)HDIM * DDIM, DDIM);
  // W2[e][h][d] -> W2t[d][e*H + h]   (oexp = H col offset, row stride E*H)
  dim3 g2(HDIM / 64, DDIM / 64, NEXP);
  k_transpose<<<g2, 256, 0, stream>>>(W2, W2t, HDIM, DDIM, (size_t)HDIM, NEXP * HDIM);
  k_gate<<<NTOK / 4, 256, 0, stream>>>(x, Wg, bg, gate);

  const int rounds = NEXP / G;
  for (int g = 0; g < rounds; ++g) {
    const int Ng = G * HDIM;                     // group N (gemm1) / K (gemm2)
    // GEMM1: h'[m][Ng] = gate*relu(xb[m][D] . W1t_slice^T + b1)
    k_gemm<1><<<(NTOK / BM) * (Ng / BN), 512, 0, stream>>>(
        xb, DDIM, W1t + (size_t)g * Ng * DDIM, DDIM,
        b1 + (size_t)g * Ng, gate, g * G,
        hbuf, Ng, Ng / BN, DDIM, 0);
    // GEMM2: out[m][D] (+)= h'[m][Ng] . W2t_slice^T  (+ sum_e gate*b2 on first)
    k_gemm<2><<<(NTOK / BM) * (DDIM / BN), 512, 0, stream>>>(
        hbuf, Ng, W2t + (size_t)g * Ng, NEXP * HDIM,
        b2, gate, 0,
        out, DDIM, DDIM / BN, Ng, g > 0);
  }
}